// Round 1
// baseline (562.815 us; speedup 1.0000x reference)
//
#include <hip/hip_runtime.h>

#define N_NODES 100000
#define DEG 16
#define DIM 128

// ---------------------------------------------------------------------------
// dense: computes z = h @ W_W^T and zi = h @ W_U^T  (both N x 128)
// grid: (ceil(N/64), 4). blockIdx.y selects 64-col block:
//   0,1 -> W_W rows 0-63 / 64-127 (writes z), 2,3 -> W_U (writes zi)
// 256 threads, each computes a 4x4 microtile of the 64(node) x 64(col) tile.
// ---------------------------------------------------------------------------
__global__ __launch_bounds__(256) void dense_kernel(
    const float* __restrict__ h,
    const float* __restrict__ W_W,
    const float* __restrict__ W_U,
    float* __restrict__ z,
    float* __restrict__ zi)
{
    __shared__ float ht[32][64];   // [k][node]
    __shared__ float wt[32][64];   // [k][col]

    const int nblk = blockIdx.x * 64;
    const int cb = blockIdx.y;                 // 0..3
    const float* Wsrc = (cb < 2 ? W_W : W_U) + (size_t)(cb & 1) * 64 * DIM;
    float* Cout = (cb < 2 ? z : zi);
    const int cbase = (cb & 1) * 64;

    const int tid = threadIdx.x;
    const int tx = tid & 15;        // col group (4 cols each)
    const int ty = tid >> 4;        // node group (4 nodes each)

    float acc[4][4] = {};

    for (int k0 = 0; k0 < DIM; k0 += 32) {
        // stage h tile (64 nodes x 32 k) and W tile (64 rows x 32 k), transposed
        // 2048 floats each = 512 float4 -> 2 float4 per thread per matrix
        for (int c = 0; c < 2; c++) {
            int chunk = tid * 2 + c;           // 0..511
            int row   = chunk >> 3;            // 0..63
            int kk    = (chunk & 7) * 4;       // 0,4,...,28

            int gn = nblk + row;
            float4 v = make_float4(0.f, 0.f, 0.f, 0.f);
            if (gn < N_NODES) v = *(const float4*)(h + (size_t)gn * DIM + k0 + kk);
            ht[kk + 0][row] = v.x; ht[kk + 1][row] = v.y;
            ht[kk + 2][row] = v.z; ht[kk + 3][row] = v.w;

            float4 wv = *(const float4*)(Wsrc + (size_t)row * DIM + k0 + kk);
            wt[kk + 0][row] = wv.x; wt[kk + 1][row] = wv.y;
            wt[kk + 2][row] = wv.z; wt[kk + 3][row] = wv.w;
        }
        __syncthreads();

        for (int kk = 0; kk < 32; kk++) {
            float4 a = *(const float4*)&ht[kk][ty * 4];
            float4 b = *(const float4*)&wt[kk][tx * 4];
            float av[4] = {a.x, a.y, a.z, a.w};
            float bv[4] = {b.x, b.y, b.z, b.w};
#pragma unroll
            for (int i = 0; i < 4; i++)
#pragma unroll
                for (int j = 0; j < 4; j++)
                    acc[i][j] += av[i] * bv[j];
        }
        __syncthreads();
    }

#pragma unroll
    for (int i = 0; i < 4; i++) {
        int gn = nblk + ty * 4 + i;
        if (gn >= N_NODES) continue;
        float4 o = make_float4(acc[i][0], acc[i][1], acc[i][2], acc[i][3]);
        *(float4*)(Cout + (size_t)gn * DIM + cbase + tx * 4) = o;
    }
}

// ---------------------------------------------------------------------------
// scores: s_src[n] = dot(z[n], W_a[0:128]), s_dst[n] = dot(z[n], W_a[128:256])
// one wave (64 lanes) per node, 4 nodes per 256-thread block
// ---------------------------------------------------------------------------
__global__ __launch_bounds__(256) void scores_kernel(
    const float* __restrict__ z,
    const float* __restrict__ W_a,   // 257 floats
    float* __restrict__ s_src,
    float* __restrict__ s_dst)
{
    int node = blockIdx.x * 4 + (threadIdx.x >> 6);
    int lane = threadIdx.x & 63;
    if (node >= N_NODES) return;

    float2 zv = *(const float2*)(z + (size_t)node * DIM + lane * 2);
    float2 as = *(const float2*)(W_a + lane * 2);
    float2 ad = *(const float2*)(W_a + DIM + lane * 2);
    float ss = zv.x * as.x + zv.y * as.y;
    float sd = zv.x * ad.x + zv.y * ad.y;
#pragma unroll
    for (int off = 32; off; off >>= 1) {
        ss += __shfl_down(ss, off);
        sd += __shfl_down(sd, off);
    }
    if (lane == 0) { s_src[node] = ss; s_dst[node] = sd; }
}

// ---------------------------------------------------------------------------
// aggr: per dst node i (16 contiguous edges i*16..i*16+15):
//   e_j = leaky_relu(s_src[src_j] + s_dst[i] + edge_d[i*16+j]*W_V*a_t)
//   softmax over the 16, zn = sum alpha_j * z[src_j], out = relu(zi[i] + zn)
// 128 threads per node (one per dim), 2 nodes per 256-thread block
// ---------------------------------------------------------------------------
__global__ __launch_bounds__(256) void aggr_kernel(
    const float* __restrict__ z,
    const float* __restrict__ zi,
    const float* __restrict__ s_src,
    const float* __restrict__ s_dst,
    const float* __restrict__ edge_d,
    const int* __restrict__ edge_src,
    const float* __restrict__ W_V,   // 1 float
    const float* __restrict__ W_a,   // a_t = W_a[256]
    float* __restrict__ out)
{
    __shared__ float ev[2][DEG];
    __shared__ int srcs[2][DEG];

    const int local = threadIdx.x >> 7;      // 0 or 1
    const int t = threadIdx.x & 127;         // dim
    const int node = blockIdx.x * 2 + local;

    if (node < N_NODES && t < DEG) {
        float coef = W_V[0] * W_a[2 * DIM];
        int e = node * DEG + t;
        int s = edge_src[e];
        srcs[local][t] = s;
        float x = s_src[s] + s_dst[node] + edge_d[e] * coef;
        ev[local][t] = x > 0.f ? x : 0.01f * x;
    }
    __syncthreads();
    if (node >= N_NODES) return;

    float m = -1e30f;
#pragma unroll
    for (int j = 0; j < DEG; j++) m = fmaxf(m, ev[local][j]);

    float ex[DEG];
    float denom = 0.f;
#pragma unroll
    for (int j = 0; j < DEG; j++) { ex[j] = __expf(ev[local][j] - m); denom += ex[j]; }
    float inv = 1.f / denom;

    float acc = 0.f;
#pragma unroll
    for (int j = 0; j < DEG; j++) {
        acc += ex[j] * inv * z[(size_t)srcs[local][j] * DIM + t];
    }

    float v = zi[(size_t)node * DIM + t] + acc;
    out[(size_t)node * DIM + t] = v > 0.f ? v : 0.f;
}

// ---------------------------------------------------------------------------
extern "C" void kernel_launch(void* const* d_in, const int* in_sizes, int n_in,
                              void* d_out, int out_size, void* d_ws, size_t ws_size,
                              hipStream_t stream) {
    const float* attr     = (const float*)d_in[0];
    const float* edge_d   = (const float*)d_in[1];
    const float* W_V1     = (const float*)d_in[2];
    const float* W_W1     = (const float*)d_in[3];
    const float* W_U1     = (const float*)d_in[4];
    const float* W_a1     = (const float*)d_in[5];
    const float* W_V2     = (const float*)d_in[6];
    const float* W_W2     = (const float*)d_in[7];
    const float* W_U2     = (const float*)d_in[8];
    const float* W_a2     = (const float*)d_in[9];
    const int*   edge_src = (const int*)d_in[10];
    // d_in[11] = edge_dst (implicit: repeat(arange(N), DEG))

    float* out = (float*)d_out;

    const size_t NROW = (size_t)N_NODES * DIM;
    float* ws = (float*)d_ws;
    float* z     = ws;                 // N*128
    float* zi    = ws + NROW;          // N*128
    float* h1    = ws + 2 * NROW;      // N*128
    float* s_src = ws + 3 * NROW;      // N
    float* s_dst = ws + 3 * NROW + N_NODES;

    dim3 dgrid((N_NODES + 63) / 64, 4);
    int sgrid = (N_NODES + 3) / 4;
    int agrid = (N_NODES + 1) / 2;

    // ---- layer 1 ----
    dense_kernel<<<dgrid, 256, 0, stream>>>(attr, W_W1, W_U1, z, zi);
    scores_kernel<<<sgrid, 256, 0, stream>>>(z, W_a1, s_src, s_dst);
    aggr_kernel<<<agrid, 256, 0, stream>>>(z, zi, s_src, s_dst, edge_d,
                                           edge_src, W_V1, W_a1, h1);

    // ---- layer 2 ----
    dense_kernel<<<dgrid, 256, 0, stream>>>(h1, W_W2, W_U2, z, zi);
    scores_kernel<<<sgrid, 256, 0, stream>>>(z, W_a2, s_src, s_dst);
    aggr_kernel<<<agrid, 256, 0, stream>>>(z, zi, s_src, s_dst, edge_d,
                                           edge_src, W_V2, W_a2, out);
}

// Round 2
// 400.922 us; speedup vs baseline: 1.4038x; 1.4038x over previous
//
#include <hip/hip_runtime.h>

#define N_NODES 100000
#define DEG 16
#define DIM 128
#define NGROUPS 6250   // N_NODES / 16 (exact)

typedef short bf16x8 __attribute__((ext_vector_type(8)));
typedef float f32x4 __attribute__((ext_vector_type(4)));

__device__ __forceinline__ unsigned short f2bf(float f) {
    unsigned int u = __builtin_bit_cast(unsigned int, f);
    u = (u + 0x7fffu + ((u >> 16) & 1u)) >> 16;
    return (unsigned short)u;
}
__device__ __forceinline__ float bf2f(unsigned short h) {
    unsigned int u = ((unsigned int)h) << 16;
    return __builtin_bit_cast(float, u);
}

// ---------------------------------------------------------------------------
// cast attr (N x 128 fp32) -> bf16, 8 elems/thread
// ---------------------------------------------------------------------------
__global__ __launch_bounds__(256) void cast_attr(
    const float* __restrict__ in, unsigned short* __restrict__ outp)
{
    int idx = blockIdx.x * 256 + threadIdx.x;       // 1.6M threads
    const float4* p = (const float4*)in + (size_t)idx * 2;
    float4 v0 = p[0], v1 = p[1];
    uint4 o;
    o.x = (unsigned int)f2bf(v0.x) | ((unsigned int)f2bf(v0.y) << 16);
    o.y = (unsigned int)f2bf(v0.z) | ((unsigned int)f2bf(v0.w) << 16);
    o.z = (unsigned int)f2bf(v1.x) | ((unsigned int)f2bf(v1.y) << 16);
    o.w = (unsigned int)f2bf(v1.z) | ((unsigned int)f2bf(v1.w) << 16);
    *(uint4*)(outp + (size_t)idx * 8) = o;
}

// ---------------------------------------------------------------------------
// build Wc (256 x 128 bf16): rows 0-127 = W_W, rows 128-255 = W_U
// ---------------------------------------------------------------------------
__global__ __launch_bounds__(256) void cast_w(
    const float* __restrict__ W_W, const float* __restrict__ W_U,
    unsigned short* __restrict__ Wc)
{
    int idx = blockIdx.x * 256 + threadIdx.x;       // 0..32767
    float v = (idx < 16384) ? W_W[idx] : W_U[idx - 16384];
    Wc[idx] = f2bf(v);
}

// ---------------------------------------------------------------------------
// dense: zcat[n][0:128] = h @ W_W^T, zcat[n][128:256] = h @ W_U^T  (bf16)
// MFMA 16x16x32 bf16. 4 waves/block, each wave: 16 nodes x 256 cols.
// A-frag: lane holds h[base+(l&15)][quad*8+j]; B-frag: Wc[ct*16+(l&15)][k..]
// C/D: col = lane&15, row = quad*4 + reg.
// ---------------------------------------------------------------------------
__global__ __launch_bounds__(256) void dense_mfma(
    const unsigned short* __restrict__ hA,   // N x 128 bf16
    const unsigned short* __restrict__ Wc,   // 256 x 128 bf16
    unsigned short* __restrict__ zcat)       // N x 256 bf16
{
    int wave = threadIdx.x >> 6;
    int lane = threadIdx.x & 63;
    int group = blockIdx.x * 4 + wave;
    if (group >= NGROUPS) return;
    int m = lane & 15;
    int quad = lane >> 4;
    int nodebase = group * 16;

    bf16x8 a[4];
    const unsigned short* arow = hA + (size_t)(nodebase + m) * DIM + quad * 8;
#pragma unroll
    for (int ks = 0; ks < 4; ks++)
        a[ks] = *(const bf16x8*)(arow + ks * 32);

#pragma unroll 4
    for (int ct = 0; ct < 16; ct++) {
        const unsigned short* brow = Wc + (size_t)(ct * 16 + m) * DIM + quad * 8;
        f32x4 acc = {0.f, 0.f, 0.f, 0.f};
#pragma unroll
        for (int ks = 0; ks < 4; ks++) {
            bf16x8 b = *(const bf16x8*)(brow + ks * 32);
            acc = __builtin_amdgcn_mfma_f32_16x16x32_bf16(a[ks], b, acc, 0, 0, 0);
        }
        int col = ct * 16 + m;
#pragma unroll
        for (int r = 0; r < 4; r++) {
            int node = nodebase + quad * 4 + r;
            zcat[(size_t)node * 256 + col] = f2bf(acc[r]);
        }
    }
}

// ---------------------------------------------------------------------------
// scores from bf16 zcat: one wave per node
// ---------------------------------------------------------------------------
__global__ __launch_bounds__(256) void scores_kernel(
    const unsigned short* __restrict__ zcat,
    const float* __restrict__ W_a,   // 257 floats
    float* __restrict__ s_src, float* __restrict__ s_dst)
{
    int node = blockIdx.x * 4 + (threadIdx.x >> 6);
    int lane = threadIdx.x & 63;
    if (node >= N_NODES) return;
    unsigned int raw = *(const unsigned int*)(zcat + (size_t)node * 256 + lane * 2);
    float z0 = bf2f((unsigned short)raw), z1 = bf2f((unsigned short)(raw >> 16));
    float2 as = *(const float2*)(W_a + lane * 2);
    float2 ad = *(const float2*)(W_a + DIM + lane * 2);
    float ss = z0 * as.x + z1 * as.y;
    float sd = z0 * ad.x + z1 * ad.y;
#pragma unroll
    for (int off = 32; off; off >>= 1) {
        ss += __shfl_down(ss, off);
        sd += __shfl_down(sd, off);
    }
    if (lane == 0) { s_src[node] = ss; s_dst[node] = sd; }
}

// ---------------------------------------------------------------------------
// aggr: one wave (64 lanes) per node, 2 dims per lane, bf16 gather
// ---------------------------------------------------------------------------
__global__ __launch_bounds__(256) void aggr_kernel(
    const unsigned short* __restrict__ zcat,
    const float* __restrict__ s_src,
    const float* __restrict__ s_dst,
    const float* __restrict__ edge_d,
    const int* __restrict__ edge_src,
    const float* __restrict__ W_V,   // 1 float
    const float* __restrict__ W_a,   // a_t = W_a[256]
    unsigned short* __restrict__ out_bf16,  // layer1 target (or null)
    float* __restrict__ out_f32)            // layer2 target (or null)
{
    __shared__ float ev[4][DEG];
    __shared__ int srcs[4][DEG];

    const int w = threadIdx.x >> 6;
    const int lane = threadIdx.x & 63;
    const int node = blockIdx.x * 4 + w;
    const bool valid = node < N_NODES;

    if (valid && lane < DEG) {
        float coef = W_V[0] * W_a[2 * DIM];
        int e = node * DEG + lane;
        int s = edge_src[e];
        srcs[w][lane] = s;
        float x = s_src[s] + s_dst[node] + edge_d[e] * coef;
        ev[w][lane] = x > 0.f ? x : 0.01f * x;
    }
    __syncthreads();
    if (!valid) return;

    float m = -1e30f;
#pragma unroll
    for (int j = 0; j < DEG; j++) m = fmaxf(m, ev[w][j]);

    float alpha[DEG];
    float denom = 0.f;
#pragma unroll
    for (int j = 0; j < DEG; j++) { alpha[j] = __expf(ev[w][j] - m); denom += alpha[j]; }
    float inv = 1.f / denom;

    float ax = 0.f, ay = 0.f;
#pragma unroll
    for (int j = 0; j < DEG; j++) {
        unsigned int raw = *(const unsigned int*)(zcat + (size_t)srcs[w][j] * 256 + lane * 2);
        float a = alpha[j] * inv;
        ax += a * bf2f((unsigned short)raw);
        ay += a * bf2f((unsigned short)(raw >> 16));
    }

    unsigned int zraw = *(const unsigned int*)(zcat + (size_t)node * 256 + 128 + lane * 2);
    float v0 = bf2f((unsigned short)zraw) + ax;
    float v1 = bf2f((unsigned short)(zraw >> 16)) + ay;
    v0 = v0 > 0.f ? v0 : 0.f;
    v1 = v1 > 0.f ? v1 : 0.f;

    if (out_f32) {
        *(float2*)(out_f32 + (size_t)node * DIM + lane * 2) = make_float2(v0, v1);
    } else {
        unsigned int packed = (unsigned int)f2bf(v0) | ((unsigned int)f2bf(v1) << 16);
        *(unsigned int*)(out_bf16 + (size_t)node * DIM + lane * 2) = packed;
    }
}

// ---------------------------------------------------------------------------
extern "C" void kernel_launch(void* const* d_in, const int* in_sizes, int n_in,
                              void* d_out, int out_size, void* d_ws, size_t ws_size,
                              hipStream_t stream) {
    const float* attr     = (const float*)d_in[0];
    const float* edge_d   = (const float*)d_in[1];
    const float* W_V1     = (const float*)d_in[2];
    const float* W_W1     = (const float*)d_in[3];
    const float* W_U1     = (const float*)d_in[4];
    const float* W_a1     = (const float*)d_in[5];
    const float* W_V2     = (const float*)d_in[6];
    const float* W_W2     = (const float*)d_in[7];
    const float* W_U2     = (const float*)d_in[8];
    const float* W_a2     = (const float*)d_in[9];
    const int*   edge_src = (const int*)d_in[10];

    float* out = (float*)d_out;

    // workspace layout (bytes)
    char* ws = (char*)d_ws;
    unsigned short* hA   = (unsigned short*)ws;                        // N*128 bf16 = 25.6 MB
    unsigned short* zcat = (unsigned short*)(ws + 26 * 1024 * 1024);   // N*256 bf16 = 51.2 MB
    unsigned short* h1   = (unsigned short*)(ws + 78 * 1024 * 1024);   // N*128 bf16 = 25.6 MB
    unsigned short* Wc1  = (unsigned short*)(ws + 104 * 1024 * 1024);  // 64 KB
    unsigned short* Wc2  = (unsigned short*)(ws + 105 * 1024 * 1024);  // 64 KB
    float* s_src         = (float*)(ws + 106 * 1024 * 1024);           // 400 KB
    float* s_dst         = (float*)(ws + 107 * 1024 * 1024);           // 400 KB

    int dgrid = (NGROUPS + 3) / 4;          // 1563
    int sgrid = (N_NODES + 3) / 4;          // 25000
    int agrid = (N_NODES + 3) / 4;          // 25000

    cast_attr<<<6250, 256, 0, stream>>>(attr, hA);
    cast_w<<<128, 256, 0, stream>>>(W_W1, W_U1, Wc1);
    cast_w<<<128, 256, 0, stream>>>(W_W2, W_U2, Wc2);

    // ---- layer 1 ----
    dense_mfma<<<dgrid, 256, 0, stream>>>(hA, Wc1, zcat);
    scores_kernel<<<sgrid, 256, 0, stream>>>(zcat, W_a1, s_src, s_dst);
    aggr_kernel<<<agrid, 256, 0, stream>>>(zcat, s_src, s_dst, edge_d,
                                           edge_src, W_V1, W_a1, h1, nullptr);

    // ---- layer 2 ----
    dense_mfma<<<dgrid, 256, 0, stream>>>(h1, Wc2, zcat);
    scores_kernel<<<sgrid, 256, 0, stream>>>(zcat, W_a2, s_src, s_dst);
    aggr_kernel<<<agrid, 256, 0, stream>>>(zcat, s_src, s_dst, edge_d,
                                           edge_src, W_V2, W_a2, nullptr, out);
}

// Round 3
// 332.283 us; speedup vs baseline: 1.6938x; 1.2066x over previous
//
#include <hip/hip_runtime.h>

#define N_NODES 100000
#define DEG 16
#define DIM 128
#define NGROUPS 6250        // N_NODES / 16
#define GPB 5               // node-groups per dense block
#define DBLOCKS (NGROUPS / GPB)   // 1250

typedef short bf16x8 __attribute__((ext_vector_type(8)));
typedef float f32x4 __attribute__((ext_vector_type(4)));

__device__ __forceinline__ unsigned short f2bf(float f) {
    unsigned int u = __builtin_bit_cast(unsigned int, f);
    u = (u + 0x7fffu + ((u >> 16) & 1u)) >> 16;
    return (unsigned short)u;
}
__device__ __forceinline__ float bf2f(unsigned short h) {
    unsigned int u = ((unsigned int)h) << 16;
    return __builtin_bit_cast(float, u);
}

// ---------------------------------------------------------------------------
// cast attr (N x 128 fp32) -> bf16, 8 elems/thread
// ---------------------------------------------------------------------------
__global__ __launch_bounds__(256) void cast_attr(
    const float* __restrict__ in, unsigned short* __restrict__ outp)
{
    int idx = blockIdx.x * 256 + threadIdx.x;
    const float4* p = (const float4*)in + (size_t)idx * 2;
    float4 v0 = p[0], v1 = p[1];
    uint4 o;
    o.x = (unsigned int)f2bf(v0.x) | ((unsigned int)f2bf(v0.y) << 16);
    o.y = (unsigned int)f2bf(v0.z) | ((unsigned int)f2bf(v0.w) << 16);
    o.z = (unsigned int)f2bf(v1.x) | ((unsigned int)f2bf(v1.y) << 16);
    o.w = (unsigned int)f2bf(v1.z) | ((unsigned int)f2bf(v1.w) << 16);
    *(uint4*)(outp + (size_t)idx * 8) = o;
}

// ---------------------------------------------------------------------------
// dense_fused: zcat[n][0:128] = h @ W_W^T, zcat[n][128:256] = h @ W_U^T (bf16)
// plus fused s_src[n] = z.a_src, s_dst[n] = z.a_dst.
// Operand-swapped MFMA: A = W rows (m = output col), B = h rows (n = node).
// C/D: n = lane&15 (node), m = quad*4 + r (4 CONSECUTIVE output cols/lane)
// -> packed uint2 stores. Wave w owns output cols [w*64, w*64+64).
// Each wave loops GPB node-groups; W frags converted fp32->bf16 once.
// ---------------------------------------------------------------------------
__global__ __launch_bounds__(256) void dense_fused(
    const unsigned short* __restrict__ hA,   // N x 128 bf16
    const float* __restrict__ W_W,           // 128 x 128 f32
    const float* __restrict__ W_U,           // 128 x 128 f32
    const float* __restrict__ W_a,           // 257 f32
    unsigned short* __restrict__ zcat,       // N x 256 bf16
    float* __restrict__ s_src,
    float* __restrict__ s_dst)
{
    __shared__ float sred[2][2][2][16];      // [g&1][wave<2][ss/sd][node16]

    const int wave = threadIdx.x >> 6;
    const int lane = threadIdx.x & 63;
    const int n16 = lane & 15;
    const int quad = lane >> 4;

    // A-operand: W rows = output cols [wave*64 .. wave*64+64)
    const float* Wbase = (wave < 2) ? (W_W + (size_t)wave * 64 * DIM)
                                    : (W_U + (size_t)(wave - 2) * 64 * DIM);
    bf16x8 wfrag[4][4];                      // [ct][ks]
#pragma unroll
    for (int ct = 0; ct < 4; ct++) {
        const float* wrow = Wbase + (size_t)(ct * 16 + n16) * DIM + quad * 8;
#pragma unroll
        for (int ks = 0; ks < 4; ks++) {
            float4 lo = *(const float4*)(wrow + ks * 32);
            float4 hi = *(const float4*)(wrow + ks * 32 + 4);
            bf16x8 f;
            f[0] = (short)f2bf(lo.x); f[1] = (short)f2bf(lo.y);
            f[2] = (short)f2bf(lo.z); f[3] = (short)f2bf(lo.w);
            f[4] = (short)f2bf(hi.x); f[5] = (short)f2bf(hi.y);
            f[6] = (short)f2bf(hi.z); f[7] = (short)f2bf(hi.w);
            wfrag[ct][ks] = f;
        }
    }

    // fused-score vectors (waves 0,1 hold z cols 0..127)
    float4 av_s[4], av_d[4];
    if (wave < 2) {
#pragma unroll
        for (int ct = 0; ct < 4; ct++) {
            av_s[ct] = *(const float4*)(W_a + wave * 64 + ct * 16 + quad * 4);
            av_d[ct] = *(const float4*)(W_a + DIM + wave * 64 + ct * 16 + quad * 4);
        }
    }

    for (int g = 0; g < GPB; g++) {
        const int nodebase = (blockIdx.x * GPB + g) * 16;

        // B-operand: 16 h rows
        bf16x8 hfrag[4];
        const unsigned short* hrow = hA + (size_t)(nodebase + n16) * DIM + quad * 8;
#pragma unroll
        for (int ks = 0; ks < 4; ks++)
            hfrag[ks] = *(const bf16x8*)(hrow + ks * 32);

        f32x4 acc[4];
#pragma unroll
        for (int ct = 0; ct < 4; ct++) {
            f32x4 a = {0.f, 0.f, 0.f, 0.f};
#pragma unroll
            for (int ks = 0; ks < 4; ks++)
                a = __builtin_amdgcn_mfma_f32_16x16x32_bf16(wfrag[ct][ks], hfrag[ks], a, 0, 0, 0);
            acc[ct] = a;
        }

        // store: node = nodebase+n16, cols wave*64 + ct*16 + quad*4 + (0..3)
        unsigned short* orow = zcat + (size_t)(nodebase + n16) * 256 + wave * 64 + quad * 4;
#pragma unroll
        for (int ct = 0; ct < 4; ct++) {
            uint2 pk;
            pk.x = (unsigned int)f2bf(acc[ct][0]) | ((unsigned int)f2bf(acc[ct][1]) << 16);
            pk.y = (unsigned int)f2bf(acc[ct][2]) | ((unsigned int)f2bf(acc[ct][3]) << 16);
            *(uint2*)(orow + ct * 16) = pk;
        }

        // fused scores (z cols only -> waves 0,1)
        if (wave < 2) {
            float ps = 0.f, pd = 0.f;
#pragma unroll
            for (int ct = 0; ct < 4; ct++) {
                ps += acc[ct][0] * av_s[ct].x + acc[ct][1] * av_s[ct].y
                    + acc[ct][2] * av_s[ct].z + acc[ct][3] * av_s[ct].w;
                pd += acc[ct][0] * av_d[ct].x + acc[ct][1] * av_d[ct].y
                    + acc[ct][2] * av_d[ct].z + acc[ct][3] * av_d[ct].w;
            }
            ps += __shfl_xor(ps, 16); ps += __shfl_xor(ps, 32);
            pd += __shfl_xor(pd, 16); pd += __shfl_xor(pd, 32);
            if (lane < 16) {
                sred[g & 1][wave][0][n16] = ps;
                sred[g & 1][wave][1][n16] = pd;
            }
        }
        __syncthreads();
        if (wave == 3) {
            if (lane < 16)
                s_src[nodebase + lane] = sred[g & 1][0][0][lane] + sred[g & 1][1][0][lane];
            else if (lane < 32)
                s_dst[nodebase + lane - 16] = sred[g & 1][0][1][lane - 16] + sred[g & 1][1][1][lane - 16];
        }
        // no second barrier: next iter writes the other sred parity buffer,
        // and writes to THIS parity can only happen after everyone passes
        // the next iteration's barrier (which requires wave 3's arrival).
    }
}

// ---------------------------------------------------------------------------
// aggr v2: 8 nodes/block.
// Phase 1 (threads 0..127, 1/edge): softmax alpha via 16-lane shfl groups
//   -> ONE exp per edge. alpha+src into LDS.
// Phase 2 (all 256, 32 threads/node, 4 cols each): uint2 bf16 gathers.
// ---------------------------------------------------------------------------
__global__ __launch_bounds__(256) void aggr_kernel(
    const unsigned short* __restrict__ zcat,
    const float* __restrict__ s_src,
    const float* __restrict__ s_dst,
    const float* __restrict__ edge_d,
    const int* __restrict__ edge_src,
    const float* __restrict__ W_V,          // 1 float
    const float* __restrict__ W_a,          // a_t = W_a[256]
    unsigned short* __restrict__ out_bf16,  // layer-1 target (or null)
    float* __restrict__ out_f32)            // layer-2 target (or null)
{
    __shared__ float alpha_s[8][DEG];
    __shared__ int   src_s[8][DEG];

    const int t = threadIdx.x;
    const int base = blockIdx.x * 8;

    if (t < 128) {
        int nl = t >> 4, j = t & 15;
        int node = base + nl;
        int e = node * DEG + j;
        int s = edge_src[e];
        float coef = W_V[0] * W_a[2 * DIM];
        float x = s_src[s] + s_dst[node] + edge_d[e] * coef;
        x = x > 0.f ? x : 0.01f * x;
        float m = x;
        m = fmaxf(m, __shfl_xor(m, 1));
        m = fmaxf(m, __shfl_xor(m, 2));
        m = fmaxf(m, __shfl_xor(m, 4));
        m = fmaxf(m, __shfl_xor(m, 8));
        float ex = __expf(x - m);
        float d = ex;
        d += __shfl_xor(d, 1); d += __shfl_xor(d, 2);
        d += __shfl_xor(d, 4); d += __shfl_xor(d, 8);
        alpha_s[nl][j] = ex / d;
        src_s[nl][j] = s;
    }
    __syncthreads();

    const int nl = t >> 5;
    const int node = base + nl;
    const int c4 = (t & 31) * 4;

    float a0 = 0.f, a1 = 0.f, a2 = 0.f, a3 = 0.f;
#pragma unroll
    for (int j = 0; j < DEG; j++) {
        int s = src_s[nl][j];           // LDS broadcast
        float a = alpha_s[nl][j];       // LDS broadcast
        uint2 raw = *(const uint2*)(zcat + (size_t)s * 256 + c4);
        a0 += a * bf2f((unsigned short)raw.x);
        a1 += a * bf2f((unsigned short)(raw.x >> 16));
        a2 += a * bf2f((unsigned short)raw.y);
        a3 += a * bf2f((unsigned short)(raw.y >> 16));
    }

    uint2 zr = *(const uint2*)(zcat + (size_t)node * 256 + 128 + c4);
    float v0 = fmaxf(bf2f((unsigned short)zr.x) + a0, 0.f);
    float v1 = fmaxf(bf2f((unsigned short)(zr.x >> 16)) + a1, 0.f);
    float v2 = fmaxf(bf2f((unsigned short)zr.y) + a2, 0.f);
    float v3 = fmaxf(bf2f((unsigned short)(zr.y >> 16)) + a3, 0.f);

    if (out_f32) {
        *(float4*)(out_f32 + (size_t)node * DIM + c4) = make_float4(v0, v1, v2, v3);
    } else {
        uint2 pk;
        pk.x = (unsigned int)f2bf(v0) | ((unsigned int)f2bf(v1) << 16);
        pk.y = (unsigned int)f2bf(v2) | ((unsigned int)f2bf(v3) << 16);
        *(uint2*)(out_bf16 + (size_t)node * DIM + c4) = pk;
    }
}

// ---------------------------------------------------------------------------
extern "C" void kernel_launch(void* const* d_in, const int* in_sizes, int n_in,
                              void* d_out, int out_size, void* d_ws, size_t ws_size,
                              hipStream_t stream) {
    const float* attr     = (const float*)d_in[0];
    const float* edge_d   = (const float*)d_in[1];
    const float* W_V1     = (const float*)d_in[2];
    const float* W_W1     = (const float*)d_in[3];
    const float* W_U1     = (const float*)d_in[4];
    const float* W_a1     = (const float*)d_in[5];
    const float* W_V2     = (const float*)d_in[6];
    const float* W_W2     = (const float*)d_in[7];
    const float* W_U2     = (const float*)d_in[8];
    const float* W_a2     = (const float*)d_in[9];
    const int*   edge_src = (const int*)d_in[10];

    float* out = (float*)d_out;

    char* ws = (char*)d_ws;
    unsigned short* hA   = (unsigned short*)ws;                        // 25.6 MB
    unsigned short* zcat = (unsigned short*)(ws + 26u * 1024 * 1024);  // 51.2 MB
    unsigned short* h1   = (unsigned short*)(ws + 78u * 1024 * 1024);  // 25.6 MB
    float* s_src         = (float*)(ws + 104u * 1024 * 1024);          // 400 KB
    float* s_dst         = (float*)(ws + 105u * 1024 * 1024);          // 400 KB

    cast_attr<<<6250, 256, 0, stream>>>(attr, hA);

    // ---- layer 1 ----
    dense_fused<<<DBLOCKS, 256, 0, stream>>>(hA, W_W1, W_U1, W_a1, zcat, s_src, s_dst);
    aggr_kernel<<<12500, 256, 0, stream>>>(zcat, s_src, s_dst, edge_d, edge_src,
                                           W_V1, W_a1, h1, nullptr);

    // ---- layer 2 ----
    dense_fused<<<DBLOCKS, 256, 0, stream>>>(h1, W_W2, W_U2, W_a2, zcat, s_src, s_dst);
    aggr_kernel<<<12500, 256, 0, stream>>>(zcat, s_src, s_dst, edge_d, edge_src,
                                           W_V2, W_a2, nullptr, out);
}